// Round 1
// baseline (230.620 us; speedup 1.0000x reference)
//
#include <hip/hip_runtime.h>

// Integrate-and-fire scan: x_seq (T=64, 128, 4096) f32 -> s_seq same shape.
//   v += x[t]; s = (v >= 1.0f); v -= s;
// Independent per column; scan over t. Pure streaming, memory-bound.

#define TSTEPS 64
#define NCOLS (128 * 4096)   // 524288 columns
#define NCOLS4 (NCOLS / 4)   // 131072 float4 column-groups

__global__ __launch_bounds__(256) void TandemIF_86096914416163_kernel(
    const float4* __restrict__ x, float4* __restrict__ out)
{
    const int c = blockIdx.x * 256 + threadIdx.x;   // grid sized exactly
    const float4* xp  = x   + c;
    float4*       op  = out + c;

    float vx = 0.0f, vy = 0.0f, vz = 0.0f, vw = 0.0f;

#pragma unroll 8
    for (int t = 0; t < TSTEPS; ++t) {
        float4 xt = xp[t * NCOLS4];     // coalesced 16B/lane, stride 2 MiB over t
        vx += xt.x; vy += xt.y; vz += xt.z; vw += xt.w;
        float sx = (vx >= 1.0f) ? 1.0f : 0.0f;
        float sy = (vy >= 1.0f) ? 1.0f : 0.0f;
        float sz = (vz >= 1.0f) ? 1.0f : 0.0f;
        float sw = (vw >= 1.0f) ? 1.0f : 0.0f;
        vx -= sx; vy -= sy; vz -= sz; vw -= sw;
        op[t * NCOLS4] = make_float4(sx, sy, sz, sw);
    }
}

extern "C" void kernel_launch(void* const* d_in, const int* in_sizes, int n_in,
                              void* d_out, int out_size, void* d_ws, size_t ws_size,
                              hipStream_t stream)
{
    const float4* x  = (const float4*)d_in[0];
    float4* out      = (float4*)d_out;
    // 131072 float4 columns / 256 threads = 512 blocks (2 blocks/CU, 8 waves/CU)
    TandemIF_86096914416163_kernel<<<dim3(NCOLS4 / 256), dim3(256), 0, stream>>>(x, out);
}

// Round 2
// 224.609 us; speedup vs baseline: 1.0268x; 1.0268x over previous
//
#include <hip/hip_runtime.h>
#include <string.h>

// Integrate-and-fire scan: x_seq (T=64, 128, 4096) f32 -> s_seq same shape.
//   v += x[t]; s = (v >= 1.0f); v -= s;
// Streaming, memory-bound. Round-1 evidence: latency-bound (2.5 TB/s, VALU 3.8%,
// occ 17%, VGPR=32 -> shallow load pipeline). Fix: float2/thread (16 waves/CU)
// + explicit 8-deep register double-buffer so 8 loads stay in flight per wave.

#define TSTEPS 64
#define NCOLS  (128 * 4096)    // 524288 columns
#define NCOLS2 (NCOLS / 2)     // 262144 float2 column-groups
#define BATCH  8               // loads in flight per wave

__global__ __launch_bounds__(256) void TandemIF_86096914416163_kernel(
    const float2* __restrict__ x, float2* __restrict__ out)
{
    const int c = blockIdx.x * 256 + threadIdx.x;   // grid sized exactly
    const float2* xp = x   + c;
    float2*       op = out + c;

    float vx = 0.0f, vy = 0.0f;
    float2 buf[2][BATCH];

    // Prime the pipeline: batch 0 in flight.
#pragma unroll
    for (int j = 0; j < BATCH; ++j)
        buf[0][j] = xp[j * NCOLS2];

    // Fully unrolled outer loop -> buffers stay in registers, ping-pong is static.
#pragma unroll
    for (int tb = 0; tb < TSTEPS / BATCH; ++tb) {
        const int cur = tb & 1, nxt = cur ^ 1;

        // Issue next batch's loads BEFORE touching current batch: since vmcnt
        // retires in order and these sit BEHIND the current batch in the queue,
        // waiting on cur[j] never waits on them -> 8 loads always outstanding.
        if (tb < TSTEPS / BATCH - 1) {
#pragma unroll
            for (int j = 0; j < BATCH; ++j)
                buf[nxt][j] = xp[((tb + 1) * BATCH + j) * NCOLS2];
        }

#pragma unroll
        for (int j = 0; j < BATCH; ++j) {
            const float2 xt = buf[cur][j];
            vx += xt.x; vy += xt.y;
            const float sx = (vx >= 1.0f) ? 1.0f : 0.0f;
            const float sy = (vy >= 1.0f) ? 1.0f : 0.0f;
            vx -= sx; vy -= sy;
            float2 s = make_float2(sx, sy);
            // Non-temporal 8B store: s is write-once/read-never; keep L2/L3 for x.
            double sbits;
            memcpy(&sbits, &s, sizeof(sbits));
            __builtin_nontemporal_store(
                sbits, reinterpret_cast<double*>(op + (tb * BATCH + j) * NCOLS2));
        }
    }
}

extern "C" void kernel_launch(void* const* d_in, const int* in_sizes, int n_in,
                              void* d_out, int out_size, void* d_ws, size_t ws_size,
                              hipStream_t stream)
{
    const float2* x = (const float2*)d_in[0];
    float2* out     = (float2*)d_out;
    // 262144 float2 columns / 256 threads = 1024 blocks (4 blocks/CU, 16 waves/CU)
    TandemIF_86096914416163_kernel<<<dim3(NCOLS2 / 256), dim3(256), 0, stream>>>(x, out);
}